// Round 2
// baseline (297.813 us; speedup 1.0000x reference)
//
#include <hip/hip_runtime.h>
#include <math.h>

#define NUM_E 6
#define DIM 1024
#define HID 256
#define NTOK 32768
#define NPB 4096   // tokens per batch (N)
#define TTYPE_UNKNOWN 5
#define ONE_MINUS_ALPHA 0.775f
#define FLOOR_TERM 0.0375f     // alpha * (1/E) = 0.225/6
#define GRP 16                 // unknown tokens per block in MLP kernel

// Closed-form top1 + hard-cap + combine for a probs vector of 6.
__device__ __forceinline__ void finalize_and_write(const float probs[NUM_E], float cap,
                                                   float* __restrict__ disp_out,
                                                   float* __restrict__ comb_out) {
    float v = probs[0];
    int bi = 0;
#pragma unroll
    for (int e = 1; e < NUM_E; ++e) {
        if (probs[e] > v) { v = probs[e]; bi = e; }
    }
    float excess = fmaxf(v - cap, 0.0f);
    float capped = v - excess;                 // min(v, cap)
    float hr_idx = fmaxf(cap - capped, 0.0f);  // headroom at the argmax slot
    float hsum = fmaxf(hr_idx + 5.0f * cap, 1e-8f);
    float disp[NUM_E];
    float other = excess * cap / hsum;
#pragma unroll
    for (int e = 0; e < NUM_E; ++e) disp[e] = other;
    disp[bi] = capped + excess * hr_idx / hsum;
    float s = 0.0f;
#pragma unroll
    for (int e = 0; e < NUM_E; ++e) s += disp[e];
    float inv = 1.0f / (s + 1e-8f);
#pragma unroll
    for (int e = 0; e < NUM_E; ++e) {
        disp_out[e] = disp[e];
        comb_out[e] = disp[e] * inv;
    }
}

// Kernel A: known tokens -> final output directly; unknown -> compacted list.
__launch_bounds__(256)
__global__ void classify_kernel(const int* __restrict__ ttypes,
                                const int* __restrict__ tarr,
                                const float* __restrict__ base,
                                float* __restrict__ out,
                                int* __restrict__ cnt,
                                int* __restrict__ list) {
    int i = blockIdx.x * blockDim.x + threadIdx.x;
    if (i >= NTOK) return;
    int ty = ttypes[i];
    if (ty == TTYPE_UNKNOWN) {
        int pos = atomicAdd(cnt, 1);
        list[pos] = i;
        return;
    }
    int b = i / NPB;
    float tnorm = (float)tarr[b] / 1000.0f;
    float cap = 0.5f + 1.1f * tnorm;
    float probs[NUM_E];
#pragma unroll
    for (int e = 0; e < NUM_E; ++e)
        probs[e] = ONE_MINUS_ALPHA * base[ty * NUM_E + e] + FLOOR_TERM;
    finalize_and_write(probs, cap,
                       out + (size_t)i * NUM_E,
                       out + (size_t)NTOK * NUM_E + (size_t)i * NUM_E);
}

// Kernel B: MLP gate for unknown tokens. GRP tokens per block, 256 threads.
// Thread tid owns hidden column tid. x values are wave-uniform -> SGPRs
// (scalar loads), W1 streamed via coalesced vector loads, LDS untouched in
// the hot loop: inner loop is v_fmac_f32 vacc, s_x, v_w1.
__launch_bounds__(256)
__global__ void mlp_kernel(const float* __restrict__ tokens,
                           const int* __restrict__ tarr,
                           const float* __restrict__ W1,
                           const float* __restrict__ b1,
                           const float* __restrict__ W2,
                           const float* __restrict__ b2,
                           float* __restrict__ out,
                           const int* __restrict__ cnt,
                           const int* __restrict__ list) {
    __shared__ float hs[GRP][HID + 1];   // +1 pad: conflict-free col writes
    __shared__ float w2s[HID * NUM_E];
    __shared__ float ls[GRP][NUM_E];

    int count = cnt[0];
    int start = blockIdx.x * GRP;
    if (start >= count) return;
    int tid = threadIdx.x;

    for (int k = tid; k < HID * NUM_E; k += 256) w2s[k] = W2[k];

    // Uniform token indices (clamp tail to count-1: duplicate tokens write
    // identical outputs -> idempotent, and removes validity branches).
    int toks[GRP];
#pragma unroll
    for (int r = 0; r < GRP; ++r) {
        int idx = start + r;
        if (idx > count - 1) idx = count - 1;
        toks[r] = __builtin_amdgcn_readfirstlane(list[idx]);
    }

    const float* __restrict__ xrow[GRP];
#pragma unroll
    for (int r = 0; r < GRP; ++r)
        xrow[r] = tokens + (size_t)toks[r] * DIM;

    const float* w1p = W1 + tid;
    float acc[GRP];
#pragma unroll
    for (int r = 0; r < GRP; ++r) acc[r] = 0.0f;

    for (int d0 = 0; d0 < DIM; d0 += 4) {
        float wa = w1p[(d0 + 0) * HID];
        float wb = w1p[(d0 + 1) * HID];
        float wc = w1p[(d0 + 2) * HID];
        float wd = w1p[(d0 + 3) * HID];
#pragma unroll
        for (int r = 0; r < GRP; ++r) {
            float4 xq = *reinterpret_cast<const float4*>(xrow[r] + d0);
            acc[r] = fmaf(xq.x, wa, acc[r]);
            acc[r] = fmaf(xq.y, wb, acc[r]);
            acc[r] = fmaf(xq.z, wc, acc[r]);
            acc[r] = fmaf(xq.w, wd, acc[r]);
        }
    }

    // exact GELU: x * 0.5 * (1 + erf(x/sqrt(2)))
    float bj = b1[tid];
#pragma unroll
    for (int r = 0; r < GRP; ++r) {
        float pre = acc[r] + bj;
        hs[r][tid] = 0.5f * pre * (1.0f + erff(pre * 0.70710678118654752f));
    }
    __syncthreads();

    // Layer 2: 96 threads, one (token, expert) dot each (tiny)
    if (tid < GRP * NUM_E) {
        int r = tid / NUM_E, e = tid % NUM_E;
        float s = 0.0f;
        for (int j = 0; j < HID; ++j) s = fmaf(hs[r][j], w2s[j * NUM_E + e], s);
        ls[r][e] = (s + b2[e]) / 0.1f;   // temperature
    }
    __syncthreads();

    // Finalize per token
    if (tid < GRP && start + tid < count) {
        int tokidx = toks[tid];
        int b = tokidx / NPB;
        float tnorm = (float)tarr[b] / 1000.0f;
        float cap = 0.5f + 1.1f * tnorm;
        float probs[NUM_E];
#pragma unroll
        for (int e = 0; e < NUM_E; ++e)
            probs[e] = ONE_MINUS_ALPHA * ls[tid][e] + FLOOR_TERM;
        finalize_and_write(probs, cap,
                           out + (size_t)tokidx * NUM_E,
                           out + (size_t)NTOK * NUM_E + (size_t)tokidx * NUM_E);
    }
}

extern "C" void kernel_launch(void* const* d_in, const int* in_sizes, int n_in,
                              void* d_out, int out_size, void* d_ws, size_t ws_size,
                              hipStream_t stream) {
    const float* tokens = (const float*)d_in[0];
    const int*   ttypes = (const int*)d_in[1];
    const int*   tarr   = (const int*)d_in[2];
    const float* W1     = (const float*)d_in[3];
    const float* b1     = (const float*)d_in[4];
    const float* W2     = (const float*)d_in[5];
    const float* b2     = (const float*)d_in[6];
    const float* base   = (const float*)d_in[7];
    float* out = (float*)d_out;

    int* cnt  = (int*)d_ws;
    int* list = (int*)d_ws + 64;   // 256 B offset; list worst case 128 KB

    hipMemsetAsync(cnt, 0, sizeof(int), stream);
    classify_kernel<<<NTOK / 256, 256, 0, stream>>>(ttypes, tarr, base, out, cnt, list);
    mlp_kernel<<<(NTOK + GRP - 1) / GRP, 256, 0, stream>>>(tokens, tarr, W1, b1, W2, b2,
                                                           out, cnt, list);
}

// Round 3
// 265.097 us; speedup vs baseline: 1.1234x; 1.1234x over previous
//
#include <hip/hip_runtime.h>
#include <math.h>

#define NUM_E 6
#define DIM 1024
#define HID 256
#define NTOK 32768
#define NPB 4096   // tokens per batch (N)
#define TTYPE_UNKNOWN 5
#define ONE_MINUS_ALPHA 0.775f
#define FLOOR_TERM 0.0375f     // alpha * (1/E)

// workspace layout (bytes)
#define WS_CNT   0
#define WS_LIST  256                                  // 32768 * 4 = 131072
#define WS_W1T   (256 * 1024)                         // 1 MB transposed W1
#define WS_H     (WS_W1T + DIM * HID * 4)             // gelu(h): NTOK x HID fp32
#define WS_NEED  ((size_t)WS_H + (size_t)NTOK * HID * 4)

typedef float v8f __attribute__((ext_vector_type(8)));

// Closed-form top1 + hard-cap + combine for a probs vector of 6.
__device__ __forceinline__ void finalize_and_write(const float probs[NUM_E], float cap,
                                                   float* __restrict__ disp_out,
                                                   float* __restrict__ comb_out) {
    float v = probs[0];
    int bi = 0;
#pragma unroll
    for (int e = 1; e < NUM_E; ++e) {
        if (probs[e] > v) { v = probs[e]; bi = e; }
    }
    float excess = fmaxf(v - cap, 0.0f);
    float capped = v - excess;                 // min(v, cap)
    float hr_idx = fmaxf(cap - capped, 0.0f);
    float hsum = fmaxf(hr_idx + 5.0f * cap, 1e-8f);
    float disp[NUM_E];
    float other = excess * cap / hsum;
#pragma unroll
    for (int e = 0; e < NUM_E; ++e) disp[e] = other;
    disp[bi] = capped + excess * hr_idx / hsum;
    float s = 0.0f;
#pragma unroll
    for (int e = 0; e < NUM_E; ++e) s += disp[e];
    float inv = 1.0f / (s + 1e-8f);
#pragma unroll
    for (int e = 0; e < NUM_E; ++e) {
        disp_out[e] = disp[e];
        comb_out[e] = disp[e] * inv;
    }
}

// Known tokens -> final output directly; unknown -> compacted list.
__launch_bounds__(256)
__global__ void classify_kernel(const int* __restrict__ ttypes,
                                const int* __restrict__ tarr,
                                const float* __restrict__ base,
                                float* __restrict__ out,
                                int* __restrict__ cnt,
                                int* __restrict__ list) {
    int i = blockIdx.x * blockDim.x + threadIdx.x;
    if (i >= NTOK) return;
    int ty = ttypes[i];
    if (ty == TTYPE_UNKNOWN) {
        int pos = atomicAdd(cnt, 1);
        list[pos] = i;
        return;
    }
    int b = i / NPB;
    float tnorm = (float)tarr[b] / 1000.0f;
    float cap = 0.5f + 1.1f * tnorm;
    float probs[NUM_E];
#pragma unroll
    for (int e = 0; e < NUM_E; ++e)
        probs[e] = ONE_MINUS_ALPHA * base[ty * NUM_E + e] + FLOOR_TERM;
    finalize_and_write(probs, cap,
                       out + (size_t)i * NUM_E,
                       out + (size_t)NTOK * NUM_E + (size_t)i * NUM_E);
}

// W1 [DIM][HID] -> W1T [HID][DIM], 32x32 LDS tiles.
__launch_bounds__(256)
__global__ void transpose_w1(const float* __restrict__ W1, float* __restrict__ W1T) {
    __shared__ float tile[32][33];
    int tx = threadIdx.x & 31, ty = threadIdx.x >> 5;   // 32 x 8
    int d0 = blockIdx.x * 32, c0 = blockIdx.y * 32;
#pragma unroll
    for (int i = 0; i < 4; ++i)
        tile[ty + i * 8][tx] = W1[(size_t)(d0 + ty + i * 8) * HID + c0 + tx];
    __syncthreads();
#pragma unroll
    for (int i = 0; i < 4; ++i)
        W1T[(size_t)(c0 + ty + i * 8) * DIM + d0 + tx] = tile[tx][ty + i * 8];
}

// Layer 1 for unknown tokens. Block = 64 tokens (lanes) x 16 cols (4 waves x 4).
// x: per-lane float4 streaming. W1T columns: wave-uniform via s_load_dwordx8.
// FMA: float2 math -> v_pk_fma_f32 with the SGPR pair as the one scalar operand.
__launch_bounds__(256)
__global__ void hidden_kernel(const float* __restrict__ tokens,
                              const float* __restrict__ W1T,
                              const float* __restrict__ b1,
                              float* __restrict__ hbuf,
                              const int* __restrict__ cnt,
                              const int* __restrict__ list) {
    int count = cnt[0];
    int g = blockIdx.x;                 // 64-token group
    if (g * 64 >= count) return;
    int lane = threadIdx.x & 63;
    int wave = threadIdx.x >> 6;
    int colbase = __builtin_amdgcn_readfirstlane(blockIdx.y * 16 + wave * 4);

    int idx = g * 64 + lane;
    if (idx > count - 1) idx = count - 1;   // duplicate tail writes are idempotent
    int tok = list[idx];
    const float* xrow = tokens + (size_t)tok * DIM;

    unsigned long long pb0 = (unsigned long long)(W1T + (size_t)(colbase + 0) * DIM);
    unsigned long long pb1 = (unsigned long long)(W1T + (size_t)(colbase + 1) * DIM);
    unsigned long long pb2 = (unsigned long long)(W1T + (size_t)(colbase + 2) * DIM);
    unsigned long long pb3 = (unsigned long long)(W1T + (size_t)(colbase + 3) * DIM);

    float2 a0 = make_float2(0.f, 0.f), a1 = a0, a2 = a0, a3 = a0;

#pragma unroll 1
    for (int d0 = 0; d0 < DIM; d0 += 8) {
        v8f w0, w1, w2, w3;
        unsigned int off = (unsigned int)(d0 * 4);
        asm volatile(
            "s_load_dwordx8 %0, %4, %8\n\t"
            "s_load_dwordx8 %1, %5, %8\n\t"
            "s_load_dwordx8 %2, %6, %8\n\t"
            "s_load_dwordx8 %3, %7, %8\n\t"
            "s_waitcnt lgkmcnt(0)"
            : "=&s"(w0), "=&s"(w1), "=&s"(w2), "=&s"(w3)
            : "s"(pb0), "s"(pb1), "s"(pb2), "s"(pb3), "s"(off));
        float4 xa = *reinterpret_cast<const float4*>(xrow + d0);
        float4 xb = *reinterpret_cast<const float4*>(xrow + d0 + 4);
        float2 x0 = make_float2(xa.x, xa.y);
        float2 x1 = make_float2(xa.z, xa.w);
        float2 x2 = make_float2(xb.x, xb.y);
        float2 x3 = make_float2(xb.z, xb.w);
        a0 += x0 * make_float2(w0[0], w0[1]);
        a0 += x1 * make_float2(w0[2], w0[3]);
        a0 += x2 * make_float2(w0[4], w0[5]);
        a0 += x3 * make_float2(w0[6], w0[7]);
        a1 += x0 * make_float2(w1[0], w1[1]);
        a1 += x1 * make_float2(w1[2], w1[3]);
        a1 += x2 * make_float2(w1[4], w1[5]);
        a1 += x3 * make_float2(w1[6], w1[7]);
        a2 += x0 * make_float2(w2[0], w2[1]);
        a2 += x1 * make_float2(w2[2], w2[3]);
        a2 += x2 * make_float2(w2[4], w2[5]);
        a2 += x3 * make_float2(w2[6], w2[7]);
        a3 += x0 * make_float2(w3[0], w3[1]);
        a3 += x1 * make_float2(w3[2], w3[3]);
        a3 += x2 * make_float2(w3[4], w3[5]);
        a3 += x3 * make_float2(w3[6], w3[7]);
    }

    float4 bq = *reinterpret_cast<const float4*>(b1 + colbase);
    float p0 = a0.x + a0.y + bq.x;
    float p1 = a1.x + a1.y + bq.y;
    float p2 = a2.x + a2.y + bq.z;
    float p3 = a3.x + a3.y + bq.w;
    const float k = 0.70710678118654752f;
    float4 hv;
    hv.x = 0.5f * p0 * (1.0f + erff(p0 * k));
    hv.y = 0.5f * p1 * (1.0f + erff(p1 * k));
    hv.z = 0.5f * p2 * (1.0f + erff(p2 * k));
    hv.w = 0.5f * p3 * (1.0f + erff(p3 * k));
    *reinterpret_cast<float4*>(hbuf + (size_t)idx * HID + colbase) = hv;
}

// Layer 2 + finalize. Block = 6 waves; wave e computes logit[slot][e] for 64 slots.
__launch_bounds__(384)
__global__ void out_kernel(const float* __restrict__ hbuf,
                           const float* __restrict__ W2,
                           const float* __restrict__ b2,
                           const int* __restrict__ tarr,
                           float* __restrict__ out,
                           const int* __restrict__ cnt,
                           const int* __restrict__ list) {
    __shared__ float w2s[HID * NUM_E];
    __shared__ float ls[64][NUM_E];
    int count = cnt[0];
    int g = blockIdx.x;
    if (g * 64 >= count) return;
    int tid = threadIdx.x;
    for (int kk = tid; kk < HID * NUM_E; kk += 384) w2s[kk] = W2[kk];
    __syncthreads();

    int lane = tid & 63;
    int e = tid >> 6;                   // 0..5
    int idx = g * 64 + lane;
    if (idx > count - 1) idx = count - 1;
    const float* hrow = hbuf + (size_t)idx * HID;
    float acc = 0.0f;
    for (int j = 0; j < HID; j += 4) {
        float4 hq = *reinterpret_cast<const float4*>(hrow + j);
        acc = fmaf(hq.x, w2s[(j + 0) * NUM_E + e], acc);
        acc = fmaf(hq.y, w2s[(j + 1) * NUM_E + e], acc);
        acc = fmaf(hq.z, w2s[(j + 2) * NUM_E + e], acc);
        acc = fmaf(hq.w, w2s[(j + 3) * NUM_E + e], acc);
    }
    ls[lane][e] = (acc + b2[e]) / 0.1f;   // temperature (keep exact div as before)
    __syncthreads();

    if (tid < 64) {
        int tokidx = list[idx];
        int b = tokidx / NPB;
        float tnorm = (float)tarr[b] / 1000.0f;
        float cap = 0.5f + 1.1f * tnorm;
        float probs[NUM_E];
#pragma unroll
        for (int ee = 0; ee < NUM_E; ++ee)
            probs[ee] = ONE_MINUS_ALPHA * ls[lane][ee] + FLOOR_TERM;
        finalize_and_write(probs, cap,
                           out + (size_t)tokidx * NUM_E,
                           out + (size_t)NTOK * NUM_E + (size_t)tokidx * NUM_E);
    }
}

// Fallback (ws too small): round-1 LDS-broadcast MLP, 16 tokens/block.
#define GRP 16
__launch_bounds__(256)
__global__ void mlp_fallback(const float* __restrict__ tokens,
                             const int* __restrict__ tarr,
                             const float* __restrict__ W1,
                             const float* __restrict__ b1,
                             const float* __restrict__ W2,
                             const float* __restrict__ b2,
                             float* __restrict__ out,
                             const int* __restrict__ cnt,
                             const int* __restrict__ list) {
    __shared__ float xs[GRP][256];
    __shared__ float hs[GRP][HID + 1];
    __shared__ float w2s[HID * NUM_E];
    __shared__ float lsbuf[GRP][NUM_E];
    __shared__ int   toks[GRP];
    int count = cnt[0];
    int start = blockIdx.x * GRP;
    if (start >= count) return;
    int nv = min(GRP, count - start);
    int tid = threadIdx.x;
    if (tid < nv) toks[tid] = list[start + tid];
    for (int k = tid; k < HID * NUM_E; k += 256) w2s[k] = W2[k];
    __syncthreads();
    float acc[GRP];
#pragma unroll
    for (int r = 0; r < GRP; ++r) acc[r] = 0.0f;
    for (int c = 0; c < DIM / 256; ++c) {
#pragma unroll
        for (int r = 0; r < GRP; ++r) {
            float v = 0.0f;
            if (r < nv) v = tokens[(size_t)toks[r] * DIM + c * 256 + tid];
            xs[r][tid] = v;
        }
        __syncthreads();
        for (int d = 0; d < 256; d += 4) {
            float w0 = W1[(size_t)(c * 256 + d + 0) * HID + tid];
            float w1_ = W1[(size_t)(c * 256 + d + 1) * HID + tid];
            float w2_ = W1[(size_t)(c * 256 + d + 2) * HID + tid];
            float w3_ = W1[(size_t)(c * 256 + d + 3) * HID + tid];
#pragma unroll
            for (int r = 0; r < GRP; ++r) {
                acc[r] = fmaf(xs[r][d + 0], w0, acc[r]);
                acc[r] = fmaf(xs[r][d + 1], w1_, acc[r]);
                acc[r] = fmaf(xs[r][d + 2], w2_, acc[r]);
                acc[r] = fmaf(xs[r][d + 3], w3_, acc[r]);
            }
        }
        __syncthreads();
    }
    float bj = b1[tid];
#pragma unroll
    for (int r = 0; r < GRP; ++r) {
        float pre = acc[r] + bj;
        hs[r][tid] = 0.5f * pre * (1.0f + erff(pre * 0.70710678118654752f));
    }
    __syncthreads();
    if (tid < GRP * NUM_E) {
        int r = tid / NUM_E, e = tid % NUM_E;
        float s = 0.0f;
        for (int j = 0; j < HID; ++j) s = fmaf(hs[r][j], w2s[j * NUM_E + e], s);
        lsbuf[r][e] = (s + b2[e]) / 0.1f;
    }
    __syncthreads();
    if (tid < nv) {
        int tokidx = toks[tid];
        int b = tokidx / NPB;
        float tnorm = (float)tarr[b] / 1000.0f;
        float cap = 0.5f + 1.1f * tnorm;
        float probs[NUM_E];
#pragma unroll
        for (int e = 0; e < NUM_E; ++e)
            probs[e] = ONE_MINUS_ALPHA * lsbuf[tid][e] + FLOOR_TERM;
        finalize_and_write(probs, cap,
                           out + (size_t)tokidx * NUM_E,
                           out + (size_t)NTOK * NUM_E + (size_t)tokidx * NUM_E);
    }
}

extern "C" void kernel_launch(void* const* d_in, const int* in_sizes, int n_in,
                              void* d_out, int out_size, void* d_ws, size_t ws_size,
                              hipStream_t stream) {
    const float* tokens = (const float*)d_in[0];
    const int*   ttypes = (const int*)d_in[1];
    const int*   tarr   = (const int*)d_in[2];
    const float* W1     = (const float*)d_in[3];
    const float* b1     = (const float*)d_in[4];
    const float* W2     = (const float*)d_in[5];
    const float* b2     = (const float*)d_in[6];
    const float* base   = (const float*)d_in[7];
    float* out = (float*)d_out;

    char* ws = (char*)d_ws;
    int*   cnt  = (int*)(ws + WS_CNT);
    int*   list = (int*)(ws + WS_LIST);

    hipMemsetAsync(cnt, 0, sizeof(int), stream);
    classify_kernel<<<NTOK / 256, 256, 0, stream>>>(ttypes, tarr, base, out, cnt, list);

    if (ws_size >= WS_NEED) {
        float* W1T  = (float*)(ws + WS_W1T);
        float* hbuf = (float*)(ws + WS_H);
        transpose_w1<<<dim3(DIM / 32, HID / 32), 256, 0, stream>>>(W1, W1T);
        hidden_kernel<<<dim3(NTOK / 64, HID / 16), 256, 0, stream>>>(tokens, W1T, b1,
                                                                     hbuf, cnt, list);
        out_kernel<<<NTOK / 64, 384, 0, stream>>>(hbuf, W2, b2, tarr, out, cnt, list);
    } else {
        mlp_fallback<<<(NTOK + GRP - 1) / GRP, 256, 0, stream>>>(tokens, tarr, W1, b1,
                                                                 W2, b2, out, cnt, list);
    }
}

// Round 5
// 92.204 us; speedup vs baseline: 3.2299x; 2.8751x over previous
//
#include <hip/hip_runtime.h>
#include <math.h>

#define NUM_E 6
#define DIM 1024
#define HID 256
#define NTOK 32768
#define NPB 4096   // tokens per batch (N)
#define TTYPE_UNKNOWN 5
#define ONE_MINUS_ALPHA 0.775f
#define FLOOR_TERM 0.0375f     // alpha * (1/E)
#define GRP 8                  // tokens per MLP block (683 working blocks)

// Closed-form top1 + hard-cap + combine for a probs vector of 6.
__device__ __forceinline__ void finalize_and_write(const float probs[NUM_E], float cap,
                                                   float* __restrict__ disp_out,
                                                   float* __restrict__ comb_out) {
    float v = probs[0];
    int bi = 0;
#pragma unroll
    for (int e = 1; e < NUM_E; ++e) {
        if (probs[e] > v) { v = probs[e]; bi = e; }
    }
    float excess = fmaxf(v - cap, 0.0f);
    float capped = v - excess;                 // min(v, cap)
    float hr_idx = fmaxf(cap - capped, 0.0f);
    float hsum = fmaxf(hr_idx + 5.0f * cap, 1e-8f);
    float disp[NUM_E];
    float other = excess * cap / hsum;
#pragma unroll
    for (int e = 0; e < NUM_E; ++e) disp[e] = other;
    disp[bi] = capped + excess * hr_idx / hsum;
    float s = 0.0f;
#pragma unroll
    for (int e = 0; e < NUM_E; ++e) s += disp[e];
    float inv = 1.0f / (s + 1e-8f);
#pragma unroll
    for (int e = 0; e < NUM_E; ++e) {
        disp_out[e] = disp[e];
        comb_out[e] = disp[e] * inv;
    }
}

// Known tokens -> final output directly; unknown -> compacted list.
__launch_bounds__(256)
__global__ void classify_kernel(const int* __restrict__ ttypes,
                                const int* __restrict__ tarr,
                                const float* __restrict__ base,
                                float* __restrict__ out,
                                int* __restrict__ cnt,
                                int* __restrict__ list) {
    int i = blockIdx.x * blockDim.x + threadIdx.x;
    if (i >= NTOK) return;
    int ty = ttypes[i];
    if (ty == TTYPE_UNKNOWN) {
        int pos = atomicAdd(cnt, 1);
        list[pos] = i;
        return;
    }
    int b = i / NPB;
    float tnorm = (float)tarr[b] / 1000.0f;
    float cap = 0.5f + 1.1f * tnorm;
    float probs[NUM_E];
#pragma unroll
    for (int e = 0; e < NUM_E; ++e)
        probs[e] = ONE_MINUS_ALPHA * base[ty * NUM_E + e] + FLOOR_TERM;
    finalize_and_write(probs, cap,
                       out + (size_t)i * NUM_E,
                       out + (size_t)NTOK * NUM_E + (size_t)i * NUM_E);
}

// MLP gate for unknown tokens. Block = 8 tokens x 256 cols, 256 threads.
// x rows staged ONCE in LDS (32 KB) -> the K-loop has no barriers.
// Thread tid owns hidden col tid: w loads coalesced (L2-resident W1),
// x via uniform-address ds_read_b128 (broadcast, conflict-free).
__launch_bounds__(256)
__global__ void mlp_kernel(const float* __restrict__ tokens,
                           const int* __restrict__ tarr,
                           const float* __restrict__ W1,
                           const float* __restrict__ b1,
                           const float* __restrict__ W2,
                           const float* __restrict__ b2,
                           float* __restrict__ out,
                           const int* __restrict__ cnt,
                           const int* __restrict__ list) {
    __shared__ float xs[GRP][DIM];       // 32 KB
    __shared__ float hs[GRP][HID + 1];   // 8.2 KB
    __shared__ float w2s[HID * NUM_E];   // 6 KB
    __shared__ float ls[GRP][NUM_E];

    int count = cnt[0];
    int start = blockIdx.x * GRP;
    if (count == 0 || start >= count) return;
    int tid = threadIdx.x;

    for (int k = tid; k < HID * NUM_E; k += 256) w2s[k] = W2[k];

    // Stage 8 token rows; each row: 256 threads x float4 = 4 KB, fully coalesced.
    int toks[GRP];
#pragma unroll
    for (int r = 0; r < GRP; ++r) {
        int idx = start + r;
        if (idx > count - 1) idx = count - 1;   // duplicate tail -> idempotent writes
        toks[r] = list[idx];
        const float4* src = reinterpret_cast<const float4*>(tokens + (size_t)toks[r] * DIM);
        reinterpret_cast<float4*>(xs[r])[tid] = src[tid];
    }
    __syncthreads();

    float acc[GRP];
#pragma unroll
    for (int r = 0; r < GRP; ++r) acc[r] = 0.0f;

    const float* w1p = W1 + tid;        // col = tid
#pragma unroll 2
    for (int k = 0; k < DIM; k += 4) {
        float w0 = w1p[(k + 0) * HID];
        float w1_ = w1p[(k + 1) * HID];
        float w2_ = w1p[(k + 2) * HID];
        float w3_ = w1p[(k + 3) * HID];
#pragma unroll
        for (int r = 0; r < GRP; ++r) {
            float4 xq = *reinterpret_cast<const float4*>(&xs[r][k]);  // broadcast b128
            acc[r] = fmaf(xq.x, w0, acc[r]);
            acc[r] = fmaf(xq.y, w1_, acc[r]);
            acc[r] = fmaf(xq.z, w2_, acc[r]);
            acc[r] = fmaf(xq.w, w3_, acc[r]);
        }
    }

    // exact GELU: x * 0.5 * (1 + erf(x/sqrt(2)))
    float bj = b1[tid];
#pragma unroll
    for (int r = 0; r < GRP; ++r) {
        float pre = acc[r] + bj;
        hs[r][tid] = 0.5f * pre * (1.0f + erff(pre * 0.70710678118654752f));
    }
    __syncthreads();

    // Layer 2: 48 threads, one (token, expert) dot each (tiny: 48x256 fmaf)
    if (tid < GRP * NUM_E) {
        int r = tid / NUM_E, e = tid % NUM_E;
        float s = 0.0f;
        for (int j = 0; j < HID; ++j) s = fmaf(hs[r][j], w2s[j * NUM_E + e], s);
        ls[r][e] = (s + b2[e]) / 0.1f;   // temperature
    }
    __syncthreads();

    // Finalize per token
    if (tid < GRP && start + tid < count) {
        int tokidx = toks[tid];
        int b = tokidx / NPB;
        float tnorm = (float)tarr[b] / 1000.0f;
        float cap = 0.5f + 1.1f * tnorm;
        float probs[NUM_E];
#pragma unroll
        for (int e = 0; e < NUM_E; ++e)
            probs[e] = ONE_MINUS_ALPHA * ls[tid][e] + FLOOR_TERM;
        finalize_and_write(probs, cap,
                           out + (size_t)tokidx * NUM_E,
                           out + (size_t)NTOK * NUM_E + (size_t)tokidx * NUM_E);
    }
}

extern "C" void kernel_launch(void* const* d_in, const int* in_sizes, int n_in,
                              void* d_out, int out_size, void* d_ws, size_t ws_size,
                              hipStream_t stream) {
    const float* tokens = (const float*)d_in[0];
    const int*   ttypes = (const int*)d_in[1];
    const int*   tarr   = (const int*)d_in[2];
    const float* W1     = (const float*)d_in[3];
    const float* b1     = (const float*)d_in[4];
    const float* W2     = (const float*)d_in[5];
    const float* b2     = (const float*)d_in[6];
    const float* base   = (const float*)d_in[7];
    float* out = (float*)d_out;

    int* cnt  = (int*)d_ws;
    int* list = (int*)d_ws + 64;   // 256 B offset; list worst case 128 KB

    hipMemsetAsync(cnt, 0, sizeof(int), stream);
    classify_kernel<<<NTOK / 256, 256, 0, stream>>>(ttypes, tarr, base, out, cnt, list);
    mlp_kernel<<<(NTOK + GRP - 1) / GRP, 256, 0, stream>>>(tokens, tarr, W1, b1, W2, b2,
                                                           out, cnt, list);
}